// Round 5
// baseline (407.329 us; speedup 1.0000x reference)
//
#include <hip/hip_runtime.h>

// Problem constants
#define S_LEN 2048
#define NH    16
#define HD    64
#define EMB   1024
#define NB    4
#define MROWS (NB * S_LEN)   // 8192

typedef __attribute__((ext_vector_type(8))) short  short8;   // 8 x bf16 bits (4 VGPRs)
typedef __attribute__((ext_vector_type(4))) float  float4_t; // MFMA C/D frag
typedef __attribute__((ext_vector_type(4))) int    int4_t;   // 16B int vector
union U8 { int4_t i; short8 s; };

__device__ __forceinline__ unsigned short f2bf(float f) {
    unsigned int x = __float_as_uint(f);
    unsigned int r = (x + 0x7fffu + ((x >> 16) & 1u)) >> 16;   // RNE
    return (unsigned short)r;
}

typedef const __attribute__((address_space(1))) unsigned int* gas_ptr;
typedef __attribute__((address_space(3))) unsigned int*       las_ptr;
__device__ __forceinline__ void gld_lds16(const void* g, void* l) {
    __builtin_amdgcn_global_load_lds((gas_ptr)g, (las_ptr)l, 16, 0, 0);
}

// Q pre-scale: 0.125 (1/sqrt(HD)) * log2(e) -> scores emerge in log2 domain
#define QSCALE 0.18033688011112042f

// ---------------------------------------------------------------------------
// elementwise fp32 -> bf16 (x), 2 elems/thread
// ---------------------------------------------------------------------------
__global__ void cvt_f32_bf16(const float* __restrict__ in,
                             unsigned short* __restrict__ out, int n2) {
    int i = blockIdx.x * blockDim.x + threadIdx.x;
    if (i < n2) {
        float2 v = ((const float2*)in)[i];
        ushort2 o; o.x = f2bf(v.x); o.y = f2bf(v.y);
        ((ushort2*)out)[i] = o;
    }
}

// ---------------------------------------------------------------------------
// fp32 transpose + convert: out_bf16[C][R] = in_f32[R][C]
// ---------------------------------------------------------------------------
__global__ void transpose_f32_bf16(const float* __restrict__ in,
                                   unsigned short* __restrict__ out, int R, int C) {
    __shared__ float tile[32][33];
    int n0 = blockIdx.x * 32, r0 = blockIdx.y * 32;
    int tx = threadIdx.x, ty = threadIdx.y;     // (32,8)
#pragma unroll
    for (int i = 0; i < 4; ++i)
        tile[ty + i * 8][tx] = in[(size_t)(r0 + ty + i * 8) * C + n0 + tx];
    __syncthreads();
#pragma unroll
    for (int i = 0; i < 4; ++i)
        out[(size_t)(n0 + ty + i * 8) * R + r0 + tx] = f2bf(tile[tx][ty + i * 8]);
}

// ---------------------------------------------------------------------------
// GEMM1: qkv = Xb[8192,1024] @ WqkvT[3072,1024]^T + bqkv(f32)
// epilogue scatters to Q[B,H,S,D] (PRE-SCALED by QSCALE), K[B,H,S,D],
// VT[B,H,D,S']  (all bf16).  VT keys are PERMUTED within each 64-key group
// (pi(k): [t4(2)|quad(2)|r(2)] -> [quad|t4|r]) so flash_attn's PV B-fragment
// is one contiguous 16B LDS read.
// ---------------------------------------------------------------------------
__global__ __launch_bounds__(256) void gemm_qkv(
    const unsigned short* __restrict__ X,
    const unsigned short* __restrict__ WT,
    const float* __restrict__ bias,
    unsigned short* __restrict__ Qb,
    unsigned short* __restrict__ Kb,
    unsigned short* __restrict__ VTb)
{
    __shared__ alignas(16) unsigned short As[128 * 32];
    __shared__ alignas(16) unsigned short Bs[128 * 32];
    const int K = 1024;
    int t = threadIdx.x;
    int wave = t >> 6, lane = t & 63, quad = lane >> 4, l = lane & 15;
    int bm = blockIdx.x * 128, bn = blockIdx.y * 128;
    int wm = (wave >> 1) * 64, wn = (wave & 1) * 64;

    float4_t z = {0.f, 0.f, 0.f, 0.f};
    float4_t acc[4][4];
#pragma unroll
    for (int i = 0; i < 4; ++i)
#pragma unroll
        for (int j = 0; j < 4; ++j) acc[i][j] = z;

    for (int kt = 0; kt < K / 32; ++kt) {
        int k0 = kt * 32;
        if (kt) __syncthreads();
#pragma unroll
        for (int it = 0; it < 2; ++it) {
            int c = t + 256 * it;
            int row = c >> 2, col = (c & 3) * 8;
            gld_lds16(&X [(size_t)(bm + row) * K + k0 + col], &As[c * 8]);
            gld_lds16(&WT[(size_t)(bn + row) * K + k0 + col], &Bs[c * 8]);
        }
        __syncthreads();
        short8 af[4], bfr[4];
#pragma unroll
        for (int i = 0; i < 4; ++i)
            af[i] = *(const short8*)&As[(wm + i * 16 + l) * 32 + quad * 8];
#pragma unroll
        for (int j = 0; j < 4; ++j)
            bfr[j] = *(const short8*)&Bs[(wn + j * 16 + l) * 32 + quad * 8];
#pragma unroll
        for (int i = 0; i < 4; ++i)
#pragma unroll
            for (int j = 0; j < 4; ++j)
                acc[i][j] = __builtin_amdgcn_mfma_f32_16x16x32_bf16(
                    af[i], bfr[j], acc[i][j], 0, 0, 0);
    }
#pragma unroll
    for (int j = 0; j < 4; ++j) {
        int gc = bn + wn + j * 16 + l;
        float bv = bias[gc];
        int which = gc >> 10, rem = gc & 1023;
        int h = rem >> 6, d = rem & 63;
        if (which == 2) {
            int bb = bm >> 11;
            size_t rowbase = ((size_t)(bb * NH + h) * HD + d) * S_LEN;
#pragma unroll
            for (int i = 0; i < 4; ++i) {
                unsigned int u0 = __float_as_uint(acc[i][j][0] + bv) + 0x8000u;
                unsigned int u1 = __float_as_uint(acc[i][j][1] + bv) + 0x8000u;
                unsigned int u2 = __float_as_uint(acc[i][j][2] + bv) + 0x8000u;
                unsigned int u3 = __float_as_uint(acc[i][j][3] + bv) + 0x8000u;
                uint2 vv;
                vv.x = __builtin_amdgcn_perm(u1, u0, 0x07060302u);
                vv.y = __builtin_amdgcn_perm(u3, u2, 0x07060302u);
                int s0 = (bm + wm + i * 16 + quad * 4) & 2047;
                // permute keys within 64-group: pi(k)= quad_k*16 + t4*4 + r
                int k6 = s0 & 63;
                int s0p = (s0 & ~63) | (((k6 >> 2) & 3) << 4) | (((k6 >> 4) & 3) << 2);
                *(uint2*)&VTb[rowbase + s0p] = vv;
            }
        } else {
#pragma unroll
            for (int i = 0; i < 4; ++i)
#pragma unroll
                for (int r = 0; r < 4; ++r) {
                    int gr = bm + wm + i * 16 + quad * 4 + r;
                    int b = gr >> 11, s = gr & 2047;
                    float ov = acc[i][j][r] + bv;
                    size_t bh2 = (size_t)(b * NH + h);
                    if (which == 0) Qb[(bh2 * S_LEN + s) * HD + d] = f2bf(ov * QSCALE);
                    else            Kb[(bh2 * S_LEN + s) * HD + d] = f2bf(ov);
                }
        }
    }
}

// ---------------------------------------------------------------------------
// Flash attention (causal), LDS-staged K/V shared across the block.
//
// ROUND 5: R3 (4 blk/CU, imbalanced, single-buf) = 92us beat R4 (2 blk/CU,
// balanced, double-buf) = 124us -> TLP dominated.  Combine all three wins:
//  - 1024 blocks; block g's 4 waves take chunks {2g,2g+1,62-2g,63-2g},
//    ONE chunk per wave (no two-pass -> lean VGPR).  Per-block compute =
//    66 wave-tiles UNIFORM; staged tiles = 32-g (mild 17..32 spread,
//    averaged over 4 blocks/CU).
//  - LDS exactly 32KB (double-buffered K/V; flush staging aliases buf0
//    after a final barrier) -> 4 blocks/CU; __launch_bounds__(256,4)
//    forces <=128 VGPR -> 16 waves/CU resident.
//  - One barrier/tile: stage(u+1) issued right after barrier publishing
//    tile u, loads fly under tile-u compute.
//  - V key-permuted in global (see gemm_qkv): PV B-frag = ONE swizzled
//    ds_read_b128 (was 4x ds_read_b64 + register assembly); conflict-free.
// ---------------------------------------------------------------------------
__global__ __launch_bounds__(256, 4) void flash_attn(
    const unsigned short* __restrict__ Qb,
    const unsigned short* __restrict__ Kb,
    const unsigned short* __restrict__ VTb,
    unsigned short* __restrict__ AO)
{
    // buf u&1: K 8KB | V 8KB  (16KB per buffer, 32KB total)
    // after final barrier: first 8704B reused as per-wave O staging
    __shared__ alignas(16) unsigned short smem[16384];

    int t = threadIdx.x, wave = t >> 6, lane = t & 63, quad = lane >> 4, cl = lane & 15;
    int blk = blockIdx.x;                        // 0..1023
    int bh = (blk & 7) + 8 * ((blk >> 3) & 7);   // XCD-pinned heads
    int g = blk >> 6;                            // 0..15
    int b = bh >> 4, h = bh & 15;
    int ci = (wave & 2) ? (62 - 2 * g + (wave & 1)) : (2 * g + (wave & 1));
    int qb = 32 * ci;
    int nkt = (ci >> 1) + 1;                     // tiles this wave computes
    int nkt_max = 32 - g;                        // tiles the block stages

    const unsigned short* Qbase = Qb  + (size_t)bh * S_LEN * HD;
    const unsigned short* Kbase = Kb  + (size_t)bh * S_LEN * HD;
    const unsigned short* Vbase = VTb + (size_t)bh * HD * S_LEN;

    float4_t z = {0.f, 0.f, 0.f, 0.f};
    short8 onesf;
#pragma unroll
    for (int i = 0; i < 8; ++i) onesf[i] = (short)0x3F80;   // bf16 1.0

    short8 bQ[2][2];
#pragma unroll
    for (int qt = 0; qt < 2; ++qt)
#pragma unroll
        for (int hh = 0; hh < 2; ++hh)
            bQ[qt][hh] = *(const short8*)&Qbase[(size_t)(qb + qt * 16 + cl) * HD + hh * 32 + quad * 8];

    float4_t acc[2][4], accs[2];
#pragma unroll
    for (int qt = 0; qt < 2; ++qt) {
        accs[qt] = z;
#pragma unroll
        for (int nb = 0; nb < 4; ++nb) acc[qt][nb] = z;
    }

    // kt-invariant swizzled LDS read offsets (bytes, relative to buffer base)
    int koff0[4], koff1[4];
#pragma unroll
    for (int t4 = 0; t4 < 4; ++t4) {
        int row = t4 * 16 + cl, sw = row & 7;
        koff0[t4] = (row << 7) | ((quad ^ sw) << 4);
        koff1[t4] = (row << 7) | (((quad + 4) ^ sw) << 4);
    }
    // V (permuted layout): B-frag for (p,quad) at 16B slot (quad*2+p)^(row&7)
    int voffB[2][4];
#pragma unroll
    for (int p = 0; p < 2; ++p)
#pragma unroll
        for (int nb = 0; nb < 4; ++nb) {
            int row = nb * 16 + cl;
            voffB[p][nb] = 8192 + ((row << 7) | (((quad * 2 + p) ^ (row & 7)) << 4));
        }

    auto stage = [&](int u) {
        int key0 = u << 6;
        unsigned short* Kd = smem + (u & 1) * 8192;   // 16KB buffer stride (shorts)
        unsigned short* Vd = Kd + 4096;
#pragma unroll
        for (int i = 0; i < 2; ++i) {
            int s = t + 256 * i;
            int row = s >> 3, c16 = (s & 7) ^ (row & 7);
            gld_lds16(&Kbase[(size_t)(key0 + row) * HD + c16 * 8], &Kd[s * 8]);
            gld_lds16(&Vbase[(size_t)row * S_LEN + key0 + c16 * 8], &Vd[s * 8]);
        }
    };

    stage(0);
    for (int u = 0; u < nkt_max; ++u) {
        __syncthreads();                   // publish buf[u&1]; fences prev reads
        if (u + 1 < nkt_max) stage(u + 1); // loads fly under this tile's compute
        if (u < nkt) {
            const char* Kc = (const char*)(smem + (u & 1) * 8192);
            int key0 = u << 6;
            short8 aK0[4], aK1[4];
#pragma unroll
            for (int t4 = 0; t4 < 4; ++t4) {
                aK0[t4] = *(const short8*)(Kc + koff0[t4]);
                aK1[t4] = *(const short8*)(Kc + koff1[t4]);
            }
            U8 bv[2][4];
#pragma unroll
            for (int p = 0; p < 2; ++p)
#pragma unroll
                for (int nb = 0; nb < 4; ++nb)
                    bv[p][nb].i = *(const int4_t*)(Kc + voffB[p][nb]);

            bool diag = (u == nkt - 1);
#pragma unroll
            for (int qt = 0; qt < 2; ++qt) {
                unsigned int pk[4][2];
#pragma unroll
                for (int t4 = 0; t4 < 4; ++t4) {
                    float4_t st = __builtin_amdgcn_mfma_f32_16x16x32_bf16(
                        aK1[t4], bQ[qt][1],
                        __builtin_amdgcn_mfma_f32_16x16x32_bf16(aK0[t4], bQ[qt][0], z, 0, 0, 0),
                        0, 0, 0);
                    unsigned int u4[4];
#pragma unroll
                    for (int r = 0; r < 4; ++r) {
                        float e = __builtin_amdgcn_exp2f(st[r]);   // Q pre-scaled
                        if (diag) {
                            int key = key0 + t4 * 16 + quad * 4 + r;
                            e = (key <= qb + qt * 16 + cl) ? e : 0.f;
                        }
                        u4[r] = __float_as_uint(e) + 0x8000u;      // round-to-bf16 bias
                    }
                    pk[t4][0] = __builtin_amdgcn_perm(u4[1], u4[0], 0x07060302u);
                    pk[t4][1] = __builtin_amdgcn_perm(u4[3], u4[2], 0x07060302u);
                }
#pragma unroll
                for (int p = 0; p < 2; ++p) {
                    U8 a; a.i = (int4_t){(int)pk[2 * p][0], (int)pk[2 * p][1],
                                         (int)pk[2 * p + 1][0], (int)pk[2 * p + 1][1]};
                    accs[qt] = __builtin_amdgcn_mfma_f32_16x16x32_bf16(
                        a.s, onesf, accs[qt], 0, 0, 0);            // row-sum (denominator)
#pragma unroll
                    for (int nb = 0; nb < 4; ++nb)
                        acc[qt][nb] = __builtin_amdgcn_mfma_f32_16x16x32_bf16(
                            a.s, bv[p][nb].s, acc[qt][nb], 0, 0, 0);
                }
            }
        }
    }

    __syncthreads();   // all waves done with K/V LDS before stg aliasing
    unsigned short* stgw = smem + wave * 1088;   // 16 rows x 68 stride (2176B)

    // epilogue: normalize + coalesced store via per-wave LDS staging
#pragma unroll
    for (int qt = 0; qt < 2; ++qt) {
        float fr[4];
#pragma unroll
        for (int r = 0; r < 4; ++r) fr[r] = 1.f / accs[qt][r];
#pragma unroll
        for (int nb = 0; nb < 4; ++nb)
#pragma unroll
            for (int r = 0; r < 4; ++r) {
                unsigned int uu = __float_as_uint(acc[qt][nb][r] * fr[r]) + 0x8000u;
                stgw[(quad * 4 + r) * 68 + nb * 16 + cl] = (unsigned short)(uu >> 16);
            }
#pragma unroll
        for (int pass = 0; pass < 4; ++pass) {
            int idx = pass * 64 + lane;
            int row = idx >> 4, part = idx & 15;
            ushort4 v = *(const ushort4*)&stgw[row * 68 + part * 4];
            *(ushort4*)&AO[((size_t)b * S_LEN + qb + qt * 16 + row) * EMB + h * HD + part * 4] = v;
        }
    }
}

// ---------------------------------------------------------------------------
// GEMM2: out_f32 = AO[8192,1024]bf16 @ WoutT[1024,1024]^T + bout(f32)
// ---------------------------------------------------------------------------
__global__ __launch_bounds__(256) void gemm_out(
    const unsigned short* __restrict__ A,
    const unsigned short* __restrict__ WT,
    const float* __restrict__ bias,
    float* __restrict__ out)
{
    __shared__ alignas(16) unsigned short As[128 * 32];
    __shared__ alignas(16) unsigned short Bs[128 * 32];
    const int K = 1024;
    int t = threadIdx.x;
    int wave = t >> 6, lane = t & 63, quad = lane >> 4, l = lane & 15;
    int bm = blockIdx.x * 128, bn = blockIdx.y * 128;
    int wm = (wave >> 1) * 64, wn = (wave & 1) * 64;

    float4_t z = {0.f, 0.f, 0.f, 0.f};
    float4_t acc[4][4];
#pragma unroll
    for (int i = 0; i < 4; ++i)
#pragma unroll
        for (int j = 0; j < 4; ++j) acc[i][j] = z;

    for (int kt = 0; kt < K / 32; ++kt) {
        int k0 = kt * 32;
        if (kt) __syncthreads();
#pragma unroll
        for (int it = 0; it < 2; ++it) {
            int c = t + 256 * it;
            int row = c >> 2, col = (c & 3) * 8;
            gld_lds16(&A [(size_t)(bm + row) * K + k0 + col], &As[c * 8]);
            gld_lds16(&WT[(size_t)(bn + row) * K + k0 + col], &Bs[c * 8]);
        }
        __syncthreads();
        short8 af[4], bfr[4];
#pragma unroll
        for (int i = 0; i < 4; ++i)
            af[i] = *(const short8*)&As[(wm + i * 16 + l) * 32 + quad * 8];
#pragma unroll
        for (int j = 0; j < 4; ++j)
            bfr[j] = *(const short8*)&Bs[(wn + j * 16 + l) * 32 + quad * 8];
#pragma unroll
        for (int i = 0; i < 4; ++i)
#pragma unroll
            for (int j = 0; j < 4; ++j)
                acc[i][j] = __builtin_amdgcn_mfma_f32_16x16x32_bf16(
                    af[i], bfr[j], acc[i][j], 0, 0, 0);
    }
#pragma unroll
    for (int j = 0; j < 4; ++j) {
        int gc = bn + wn + j * 16 + l;
        float bv = bias[gc];
#pragma unroll
        for (int i = 0; i < 4; ++i) {
#pragma unroll
            for (int r = 0; r < 4; ++r) {
                int gr = bm + wm + i * 16 + quad * 4 + r;
                out[(size_t)gr * EMB + gc] = acc[i][j][r] + bv;
            }
        }
    }
}

// ---------------------------------------------------------------------------
extern "C" void kernel_launch(void* const* d_in, const int* in_sizes, int n_in,
                              void* d_out, int out_size, void* d_ws, size_t ws_size,
                              hipStream_t stream) {
    const float* x    = (const float*)d_in[0];
    // d_in[1] = causal mask (int32 tril) -- implemented analytically, not read
    const float* Wqkv = (const float*)d_in[2];
    const float* bqkv = (const float*)d_in[3];
    const float* Wout = (const float*)d_in[4];
    const float* bout = (const float*)d_in[5];
    float* out = (float*)d_out;

    // workspace (bf16): Q 16MB | K 16MB | VT 16MB | Xb/AO 16MB (aliased) |
    // WqkvT 6MB | WoutT 2MB = 72MB
    char* ws = (char*)d_ws;
    const size_t SZ = (size_t)NB * NH * S_LEN * HD * 2;  // 16 MiB
    unsigned short* Qb    = (unsigned short*)(ws);
    unsigned short* Kb    = (unsigned short*)(ws + SZ);
    unsigned short* VTb   = (unsigned short*)(ws + 2 * SZ);
    unsigned short* Xb    = (unsigned short*)(ws + 3 * SZ);
    unsigned short* AO    = (unsigned short*)(ws + 3 * SZ);  // alias with Xb
    unsigned short* WqkvT = (unsigned short*)(ws + 4 * SZ);
    unsigned short* WoutT = (unsigned short*)(ws + 4 * SZ + (size_t)3 * EMB * EMB * 2);

    int n2 = MROWS * EMB / 2;
    cvt_f32_bf16<<<dim3((n2 + 255) / 256), 256, 0, stream>>>(x, Xb, n2);
    dim3 tb(32, 8);
    transpose_f32_bf16<<<dim3(3 * EMB / 32, EMB / 32), tb, 0, stream>>>(Wqkv, WqkvT, EMB, 3 * EMB);
    transpose_f32_bf16<<<dim3(EMB / 32, EMB / 32), tb, 0, stream>>>(Wout, WoutT, EMB, EMB);
    gemm_qkv<<<dim3(MROWS / 128, 3 * EMB / 128), 256, 0, stream>>>(Xb, WqkvT, bqkv, Qb, Kb, VTb);
    flash_attn<<<dim3(1024), 256, 0, stream>>>(Qb, Kb, VTb, AO);
    gemm_out<<<dim3(MROWS / 128, EMB / 128), 256, 0, stream>>>(AO, WoutT, bout, out);
}

// Round 6
// 270.038 us; speedup vs baseline: 1.5084x; 1.5084x over previous
//
#include <hip/hip_runtime.h>

// Problem constants
#define S_LEN 2048
#define NH    16
#define HD    64
#define EMB   1024
#define NB    4
#define MROWS (NB * S_LEN)   // 8192

typedef __attribute__((ext_vector_type(8))) short  short8;   // 8 x bf16 bits (4 VGPRs)
typedef __attribute__((ext_vector_type(4))) float  float4_t; // MFMA C/D frag
typedef __attribute__((ext_vector_type(4))) int    int4_t;   // 16B int vector
union U8 { int4_t i; short8 s; };

__device__ __forceinline__ unsigned short f2bf(float f) {
    unsigned int x = __float_as_uint(f);
    unsigned int r = (x + 0x7fffu + ((x >> 16) & 1u)) >> 16;   // RNE
    return (unsigned short)r;
}

typedef const __attribute__((address_space(1))) unsigned int* gas_ptr;
typedef __attribute__((address_space(3))) unsigned int*       las_ptr;
__device__ __forceinline__ void gld_lds16(const void* g, void* l) {
    __builtin_amdgcn_global_load_lds((gas_ptr)g, (las_ptr)l, 16, 0, 0);
}

// Q pre-scale: 0.125 (1/sqrt(HD)) * log2(e) -> scores emerge in log2 domain
#define QSCALE 0.18033688011112042f

// ---------------------------------------------------------------------------
// elementwise fp32 -> bf16 (x), 2 elems/thread
// ---------------------------------------------------------------------------
__global__ void cvt_f32_bf16(const float* __restrict__ in,
                             unsigned short* __restrict__ out, int n2) {
    int i = blockIdx.x * blockDim.x + threadIdx.x;
    if (i < n2) {
        float2 v = ((const float2*)in)[i];
        ushort2 o; o.x = f2bf(v.x); o.y = f2bf(v.y);
        ((ushort2*)out)[i] = o;
    }
}

// ---------------------------------------------------------------------------
// fp32 transpose + convert: out_bf16[C][R] = in_f32[R][C]
// ---------------------------------------------------------------------------
__global__ void transpose_f32_bf16(const float* __restrict__ in,
                                   unsigned short* __restrict__ out, int R, int C) {
    __shared__ float tile[32][33];
    int n0 = blockIdx.x * 32, r0 = blockIdx.y * 32;
    int tx = threadIdx.x, ty = threadIdx.y;     // (32,8)
#pragma unroll
    for (int i = 0; i < 4; ++i)
        tile[ty + i * 8][tx] = in[(size_t)(r0 + ty + i * 8) * C + n0 + tx];
    __syncthreads();
#pragma unroll
    for (int i = 0; i < 4; ++i)
        out[(size_t)(n0 + ty + i * 8) * R + r0 + tx] = f2bf(tile[tx][ty + i * 8]);
}

// ---------------------------------------------------------------------------
// GEMM1: qkv = Xb[8192,1024] @ WqkvT[3072,1024]^T + bqkv(f32)
// epilogue scatters to Q[B,H,S,D] (PRE-SCALED by QSCALE), K[B,H,S,D],
// VT[B,H,D,S']  (all bf16).  VT keys are PERMUTED within each 64-key group
// (pi(k): [t4(2)|quad(2)|r(2)] -> [quad|t4|r]) so flash_attn's PV B-fragment
// is one contiguous 16B LDS read.
// ---------------------------------------------------------------------------
__global__ __launch_bounds__(256) void gemm_qkv(
    const unsigned short* __restrict__ X,
    const unsigned short* __restrict__ WT,
    const float* __restrict__ bias,
    unsigned short* __restrict__ Qb,
    unsigned short* __restrict__ Kb,
    unsigned short* __restrict__ VTb)
{
    __shared__ alignas(16) unsigned short As[128 * 32];
    __shared__ alignas(16) unsigned short Bs[128 * 32];
    const int K = 1024;
    int t = threadIdx.x;
    int wave = t >> 6, lane = t & 63, quad = lane >> 4, l = lane & 15;
    int bm = blockIdx.x * 128, bn = blockIdx.y * 128;
    int wm = (wave >> 1) * 64, wn = (wave & 1) * 64;

    float4_t z = {0.f, 0.f, 0.f, 0.f};
    float4_t acc[4][4];
#pragma unroll
    for (int i = 0; i < 4; ++i)
#pragma unroll
        for (int j = 0; j < 4; ++j) acc[i][j] = z;

    for (int kt = 0; kt < K / 32; ++kt) {
        int k0 = kt * 32;
        if (kt) __syncthreads();
#pragma unroll
        for (int it = 0; it < 2; ++it) {
            int c = t + 256 * it;
            int row = c >> 2, col = (c & 3) * 8;
            gld_lds16(&X [(size_t)(bm + row) * K + k0 + col], &As[c * 8]);
            gld_lds16(&WT[(size_t)(bn + row) * K + k0 + col], &Bs[c * 8]);
        }
        __syncthreads();
        short8 af[4], bfr[4];
#pragma unroll
        for (int i = 0; i < 4; ++i)
            af[i] = *(const short8*)&As[(wm + i * 16 + l) * 32 + quad * 8];
#pragma unroll
        for (int j = 0; j < 4; ++j)
            bfr[j] = *(const short8*)&Bs[(wn + j * 16 + l) * 32 + quad * 8];
#pragma unroll
        for (int i = 0; i < 4; ++i)
#pragma unroll
            for (int j = 0; j < 4; ++j)
                acc[i][j] = __builtin_amdgcn_mfma_f32_16x16x32_bf16(
                    af[i], bfr[j], acc[i][j], 0, 0, 0);
    }
#pragma unroll
    for (int j = 0; j < 4; ++j) {
        int gc = bn + wn + j * 16 + l;
        float bv = bias[gc];
        int which = gc >> 10, rem = gc & 1023;
        int h = rem >> 6, d = rem & 63;
        if (which == 2) {
            int bb = bm >> 11;
            size_t rowbase = ((size_t)(bb * NH + h) * HD + d) * S_LEN;
#pragma unroll
            for (int i = 0; i < 4; ++i) {
                unsigned int u0 = __float_as_uint(acc[i][j][0] + bv) + 0x8000u;
                unsigned int u1 = __float_as_uint(acc[i][j][1] + bv) + 0x8000u;
                unsigned int u2 = __float_as_uint(acc[i][j][2] + bv) + 0x8000u;
                unsigned int u3 = __float_as_uint(acc[i][j][3] + bv) + 0x8000u;
                uint2 vv;
                vv.x = __builtin_amdgcn_perm(u1, u0, 0x07060302u);
                vv.y = __builtin_amdgcn_perm(u3, u2, 0x07060302u);
                int s0 = (bm + wm + i * 16 + quad * 4) & 2047;
                // permute keys within 64-group: pi(k)= quad_k*16 + t4*4 + r
                int k6 = s0 & 63;
                int s0p = (s0 & ~63) | (((k6 >> 2) & 3) << 4) | (((k6 >> 4) & 3) << 2);
                *(uint2*)&VTb[rowbase + s0p] = vv;
            }
        } else {
#pragma unroll
            for (int i = 0; i < 4; ++i)
#pragma unroll
                for (int r = 0; r < 4; ++r) {
                    int gr = bm + wm + i * 16 + quad * 4 + r;
                    int b = gr >> 11, s = gr & 2047;
                    float ov = acc[i][j][r] + bv;
                    size_t bh2 = (size_t)(b * NH + h);
                    if (which == 0) Qb[(bh2 * S_LEN + s) * HD + d] = f2bf(ov * QSCALE);
                    else            Kb[(bh2 * S_LEN + s) * HD + d] = f2bf(ov);
                }
        }
    }
}

// ---------------------------------------------------------------------------
// Flash attention (causal), LDS-staged K/V shared across the block.
//
// ROUND 6: R5's regression was ONE line: __launch_bounds__(256,4) squeezed
// the VGPR budget to 64 (empirical: (256,2)->128, (256,4)->64) while the
// body needs ~104 live VGPRs -> full fragment set spilled to scratch
// (FETCH 330MB / WRITE 310MB of spill traffic).  Relax to (256,2): cap 128,
// no spill; VGPR<=128 still allows 4 waves/SIMD and LDS 32KB allows
// 5 blocks/CU -> 4 blocks/CU resident (R3's winning TLP) with R5's
// balance + double-buffer + permuted-V kept:
//  - 1024 blocks; block g's 4 waves take chunks {2g,2g+1,62-2g,63-2g},
//    one chunk per wave; per-block compute = 66 wave-tiles uniform.
//  - LDS 32KB double-buffer, ONE barrier/tile; stage(u+1) issued right
//    after the barrier publishing tile u (loads fly under compute).
//  - V key-permuted in global: PV B-frag = one swizzled ds_read_b128.
// ---------------------------------------------------------------------------
__global__ __launch_bounds__(256, 2) void flash_attn(
    const unsigned short* __restrict__ Qb,
    const unsigned short* __restrict__ Kb,
    const unsigned short* __restrict__ VTb,
    unsigned short* __restrict__ AO)
{
    // buf u&1: K 8KB | V 8KB  (16KB per buffer, 32KB total)
    // after final barrier: first 8704B reused as per-wave O staging
    __shared__ alignas(16) unsigned short smem[16384];

    int t = threadIdx.x, wave = t >> 6, lane = t & 63, quad = lane >> 4, cl = lane & 15;
    int blk = blockIdx.x;                        // 0..1023
    int bh = (blk & 7) + 8 * ((blk >> 3) & 7);   // XCD-pinned heads
    int g = blk >> 6;                            // 0..15
    int b = bh >> 4, h = bh & 15;
    int ci = (wave & 2) ? (62 - 2 * g + (wave & 1)) : (2 * g + (wave & 1));
    int qb = 32 * ci;
    int nkt = (ci >> 1) + 1;                     // tiles this wave computes
    int nkt_max = 32 - g;                        // tiles the block stages

    const unsigned short* Qbase = Qb  + (size_t)bh * S_LEN * HD;
    const unsigned short* Kbase = Kb  + (size_t)bh * S_LEN * HD;
    const unsigned short* Vbase = VTb + (size_t)bh * HD * S_LEN;

    float4_t z = {0.f, 0.f, 0.f, 0.f};
    short8 onesf;
#pragma unroll
    for (int i = 0; i < 8; ++i) onesf[i] = (short)0x3F80;   // bf16 1.0

    short8 bQ[2][2];
#pragma unroll
    for (int qt = 0; qt < 2; ++qt)
#pragma unroll
        for (int hh = 0; hh < 2; ++hh)
            bQ[qt][hh] = *(const short8*)&Qbase[(size_t)(qb + qt * 16 + cl) * HD + hh * 32 + quad * 8];

    float4_t acc[2][4], accs[2];
#pragma unroll
    for (int qt = 0; qt < 2; ++qt) {
        accs[qt] = z;
#pragma unroll
        for (int nb = 0; nb < 4; ++nb) acc[qt][nb] = z;
    }

    // kt-invariant swizzled LDS read offsets (bytes, relative to buffer base)
    int koff0[4], koff1[4];
#pragma unroll
    for (int t4 = 0; t4 < 4; ++t4) {
        int row = t4 * 16 + cl, sw = row & 7;
        koff0[t4] = (row << 7) | ((quad ^ sw) << 4);
        koff1[t4] = (row << 7) | (((quad + 4) ^ sw) << 4);
    }
    // V (permuted layout): B-frag for (p,quad) at 16B slot (quad*2+p)^(row&7)
    int voffB[2][4];
#pragma unroll
    for (int p = 0; p < 2; ++p)
#pragma unroll
        for (int nb = 0; nb < 4; ++nb) {
            int row = nb * 16 + cl;
            voffB[p][nb] = 8192 + ((row << 7) | (((quad * 2 + p) ^ (row & 7)) << 4));
        }

    auto stage = [&](int u) {
        int key0 = u << 6;
        unsigned short* Kd = smem + (u & 1) * 8192;   // 16KB buffer stride (shorts)
        unsigned short* Vd = Kd + 4096;
#pragma unroll
        for (int i = 0; i < 2; ++i) {
            int s = t + 256 * i;
            int row = s >> 3, c16 = (s & 7) ^ (row & 7);
            gld_lds16(&Kbase[(size_t)(key0 + row) * HD + c16 * 8], &Kd[s * 8]);
            gld_lds16(&Vbase[(size_t)row * S_LEN + key0 + c16 * 8], &Vd[s * 8]);
        }
    };

    stage(0);
    for (int u = 0; u < nkt_max; ++u) {
        __syncthreads();                   // publish buf[u&1]; fences prev reads
        if (u + 1 < nkt_max) stage(u + 1); // loads fly under this tile's compute
        if (u < nkt) {
            const char* Kc = (const char*)(smem + (u & 1) * 8192);
            int key0 = u << 6;
            short8 aK0[4], aK1[4];
#pragma unroll
            for (int t4 = 0; t4 < 4; ++t4) {
                aK0[t4] = *(const short8*)(Kc + koff0[t4]);
                aK1[t4] = *(const short8*)(Kc + koff1[t4]);
            }
            U8 bv[2][4];
#pragma unroll
            for (int p = 0; p < 2; ++p)
#pragma unroll
                for (int nb = 0; nb < 4; ++nb)
                    bv[p][nb].i = *(const int4_t*)(Kc + voffB[p][nb]);

            bool diag = (u == nkt - 1);
#pragma unroll
            for (int qt = 0; qt < 2; ++qt) {
                unsigned int pk[4][2];
#pragma unroll
                for (int t4 = 0; t4 < 4; ++t4) {
                    float4_t st = __builtin_amdgcn_mfma_f32_16x16x32_bf16(
                        aK1[t4], bQ[qt][1],
                        __builtin_amdgcn_mfma_f32_16x16x32_bf16(aK0[t4], bQ[qt][0], z, 0, 0, 0),
                        0, 0, 0);
                    unsigned int u4[4];
#pragma unroll
                    for (int r = 0; r < 4; ++r) {
                        float e = __builtin_amdgcn_exp2f(st[r]);   // Q pre-scaled
                        if (diag) {
                            int key = key0 + t4 * 16 + quad * 4 + r;
                            e = (key <= qb + qt * 16 + cl) ? e : 0.f;
                        }
                        u4[r] = __float_as_uint(e) + 0x8000u;      // round-to-bf16 bias
                    }
                    pk[t4][0] = __builtin_amdgcn_perm(u4[1], u4[0], 0x07060302u);
                    pk[t4][1] = __builtin_amdgcn_perm(u4[3], u4[2], 0x07060302u);
                }
#pragma unroll
                for (int p = 0; p < 2; ++p) {
                    U8 a; a.i = (int4_t){(int)pk[2 * p][0], (int)pk[2 * p][1],
                                         (int)pk[2 * p + 1][0], (int)pk[2 * p + 1][1]};
                    accs[qt] = __builtin_amdgcn_mfma_f32_16x16x32_bf16(
                        a.s, onesf, accs[qt], 0, 0, 0);            // row-sum (denominator)
#pragma unroll
                    for (int nb = 0; nb < 4; ++nb)
                        acc[qt][nb] = __builtin_amdgcn_mfma_f32_16x16x32_bf16(
                            a.s, bv[p][nb].s, acc[qt][nb], 0, 0, 0);
                }
            }
        }
    }

    __syncthreads();   // all waves done with K/V LDS before stg aliasing
    unsigned short* stgw = smem + wave * 1088;   // 16 rows x 68 stride (2176B)

    // epilogue: normalize + coalesced store via per-wave LDS staging
#pragma unroll
    for (int qt = 0; qt < 2; ++qt) {
        float fr[4];
#pragma unroll
        for (int r = 0; r < 4; ++r) fr[r] = 1.f / accs[qt][r];
#pragma unroll
        for (int nb = 0; nb < 4; ++nb)
#pragma unroll
            for (int r = 0; r < 4; ++r) {
                unsigned int uu = __float_as_uint(acc[qt][nb][r] * fr[r]) + 0x8000u;
                stgw[(quad * 4 + r) * 68 + nb * 16 + cl] = (unsigned short)(uu >> 16);
            }
#pragma unroll
        for (int pass = 0; pass < 4; ++pass) {
            int idx = pass * 64 + lane;
            int row = idx >> 4, part = idx & 15;
            ushort4 v = *(const ushort4*)&stgw[row * 68 + part * 4];
            *(ushort4*)&AO[((size_t)b * S_LEN + qb + qt * 16 + row) * EMB + h * HD + part * 4] = v;
        }
    }
}

// ---------------------------------------------------------------------------
// GEMM2: out_f32 = AO[8192,1024]bf16 @ WoutT[1024,1024]^T + bout(f32)
// ---------------------------------------------------------------------------
__global__ __launch_bounds__(256) void gemm_out(
    const unsigned short* __restrict__ A,
    const unsigned short* __restrict__ WT,
    const float* __restrict__ bias,
    float* __restrict__ out)
{
    __shared__ alignas(16) unsigned short As[128 * 32];
    __shared__ alignas(16) unsigned short Bs[128 * 32];
    const int K = 1024;
    int t = threadIdx.x;
    int wave = t >> 6, lane = t & 63, quad = lane >> 4, l = lane & 15;
    int bm = blockIdx.x * 128, bn = blockIdx.y * 128;
    int wm = (wave >> 1) * 64, wn = (wave & 1) * 64;

    float4_t z = {0.f, 0.f, 0.f, 0.f};
    float4_t acc[4][4];
#pragma unroll
    for (int i = 0; i < 4; ++i)
#pragma unroll
        for (int j = 0; j < 4; ++j) acc[i][j] = z;

    for (int kt = 0; kt < K / 32; ++kt) {
        int k0 = kt * 32;
        if (kt) __syncthreads();
#pragma unroll
        for (int it = 0; it < 2; ++it) {
            int c = t + 256 * it;
            int row = c >> 2, col = (c & 3) * 8;
            gld_lds16(&A [(size_t)(bm + row) * K + k0 + col], &As[c * 8]);
            gld_lds16(&WT[(size_t)(bn + row) * K + k0 + col], &Bs[c * 8]);
        }
        __syncthreads();
        short8 af[4], bfr[4];
#pragma unroll
        for (int i = 0; i < 4; ++i)
            af[i] = *(const short8*)&As[(wm + i * 16 + l) * 32 + quad * 8];
#pragma unroll
        for (int j = 0; j < 4; ++j)
            bfr[j] = *(const short8*)&Bs[(wn + j * 16 + l) * 32 + quad * 8];
#pragma unroll
        for (int i = 0; i < 4; ++i)
#pragma unroll
            for (int j = 0; j < 4; ++j)
                acc[i][j] = __builtin_amdgcn_mfma_f32_16x16x32_bf16(
                    af[i], bfr[j], acc[i][j], 0, 0, 0);
    }
#pragma unroll
    for (int j = 0; j < 4; ++j) {
        int gc = bn + wn + j * 16 + l;
        float bv = bias[gc];
#pragma unroll
        for (int i = 0; i < 4; ++i) {
#pragma unroll
            for (int r = 0; r < 4; ++r) {
                int gr = bm + wm + i * 16 + quad * 4 + r;
                out[(size_t)gr * EMB + gc] = acc[i][j][r] + bv;
            }
        }
    }
}

// ---------------------------------------------------------------------------
extern "C" void kernel_launch(void* const* d_in, const int* in_sizes, int n_in,
                              void* d_out, int out_size, void* d_ws, size_t ws_size,
                              hipStream_t stream) {
    const float* x    = (const float*)d_in[0];
    // d_in[1] = causal mask (int32 tril) -- implemented analytically, not read
    const float* Wqkv = (const float*)d_in[2];
    const float* bqkv = (const float*)d_in[3];
    const float* Wout = (const float*)d_in[4];
    const float* bout = (const float*)d_in[5];
    float* out = (float*)d_out;

    // workspace (bf16): Q 16MB | K 16MB | VT 16MB | Xb/AO 16MB (aliased) |
    // WqkvT 6MB | WoutT 2MB = 72MB
    char* ws = (char*)d_ws;
    const size_t SZ = (size_t)NB * NH * S_LEN * HD * 2;  // 16 MiB
    unsigned short* Qb    = (unsigned short*)(ws);
    unsigned short* Kb    = (unsigned short*)(ws + SZ);
    unsigned short* VTb   = (unsigned short*)(ws + 2 * SZ);
    unsigned short* Xb    = (unsigned short*)(ws + 3 * SZ);
    unsigned short* AO    = (unsigned short*)(ws + 3 * SZ);  // alias with Xb
    unsigned short* WqkvT = (unsigned short*)(ws + 4 * SZ);
    unsigned short* WoutT = (unsigned short*)(ws + 4 * SZ + (size_t)3 * EMB * EMB * 2);

    int n2 = MROWS * EMB / 2;
    cvt_f32_bf16<<<dim3((n2 + 255) / 256), 256, 0, stream>>>(x, Xb, n2);
    dim3 tb(32, 8);
    transpose_f32_bf16<<<dim3(3 * EMB / 32, EMB / 32), tb, 0, stream>>>(Wqkv, WqkvT, EMB, 3 * EMB);
    transpose_f32_bf16<<<dim3(EMB / 32, EMB / 32), tb, 0, stream>>>(Wout, WoutT, EMB, EMB);
    gemm_qkv<<<dim3(MROWS / 128, 3 * EMB / 128), 256, 0, stream>>>(Xb, WqkvT, bqkv, Qb, Kb, VTb);
    flash_attn<<<dim3(1024), 256, 0, stream>>>(Qb, Kb, VTb, AO);
    gemm_out<<<dim3(MROWS / 128, EMB / 128), 256, 0, stream>>>(AO, WoutT, bout, out);
}

// Round 7
// 248.420 us; speedup vs baseline: 1.6397x; 1.0870x over previous
//
#include <hip/hip_runtime.h>

// Problem constants
#define S_LEN 2048
#define NH    16
#define HD    64
#define EMB   1024
#define NB    4
#define MROWS (NB * S_LEN)   // 8192

typedef __attribute__((ext_vector_type(8))) short  short8;   // 8 x bf16 bits (4 VGPRs)
typedef __attribute__((ext_vector_type(4))) float  float4_t; // MFMA C/D frag
typedef __attribute__((ext_vector_type(4))) int    int4_t;   // 16B int vector
union U8 { int4_t i; short8 s; };

__device__ __forceinline__ unsigned short f2bf(float f) {
    unsigned int x = __float_as_uint(f);
    unsigned int r = (x + 0x7fffu + ((x >> 16) & 1u)) >> 16;   // RNE
    return (unsigned short)r;
}

__device__ __forceinline__ unsigned int cvtpk_bf16(float lo, float hi) {
    unsigned int r;
    asm("v_cvt_pk_bf16_f32 %0, %1, %2" : "=v"(r) : "v"(lo), "v"(hi));
    return r;   // lo16 = bf16(lo), hi16 = bf16(hi), RNE
}

typedef const __attribute__((address_space(1))) unsigned int* gas_ptr;
typedef __attribute__((address_space(3))) unsigned int*       las_ptr;
__device__ __forceinline__ void gld_lds16(const void* g, void* l) {
    __builtin_amdgcn_global_load_lds((gas_ptr)g, (las_ptr)l, 16, 0, 0);
}

template<bool B> struct BoolC { static constexpr bool v = B; };

// Q pre-scale: 0.125 (1/sqrt(HD)) * log2(e) -> scores emerge in log2 domain
#define QSCALE 0.18033688011112042f

// ---------------------------------------------------------------------------
// elementwise fp32 -> bf16 (x), 2 elems/thread
// ---------------------------------------------------------------------------
__global__ void cvt_f32_bf16(const float* __restrict__ in,
                             unsigned short* __restrict__ out, int n2) {
    int i = blockIdx.x * blockDim.x + threadIdx.x;
    if (i < n2) {
        float2 v = ((const float2*)in)[i];
        ushort2 o; o.x = f2bf(v.x); o.y = f2bf(v.y);
        ((ushort2*)out)[i] = o;
    }
}

// ---------------------------------------------------------------------------
// fp32 transpose + convert: out_bf16[C][R] = in_f32[R][C]
// ---------------------------------------------------------------------------
__global__ void transpose_f32_bf16(const float* __restrict__ in,
                                   unsigned short* __restrict__ out, int R, int C) {
    __shared__ float tile[32][33];
    int n0 = blockIdx.x * 32, r0 = blockIdx.y * 32;
    int tx = threadIdx.x, ty = threadIdx.y;     // (32,8)
#pragma unroll
    for (int i = 0; i < 4; ++i)
        tile[ty + i * 8][tx] = in[(size_t)(r0 + ty + i * 8) * C + n0 + tx];
    __syncthreads();
#pragma unroll
    for (int i = 0; i < 4; ++i)
        out[(size_t)(n0 + ty + i * 8) * R + r0 + tx] = f2bf(tile[tx][ty + i * 8]);
}

// ---------------------------------------------------------------------------
// GEMM1: qkv = Xb[8192,1024] @ WqkvT[3072,1024]^T + bqkv(f32)
// epilogue scatters to Q[B,H,S,D] (PRE-SCALED by QSCALE), K[B,H,S,D],
// VT[B,H,D,S']  (all bf16).  VT keys are PERMUTED within each 64-key group
// (pi(k): [t4(2)|quad(2)|r(2)] -> [quad|t4|r]) so flash_attn's PV B-fragment
// is one contiguous 16B LDS read.
// ---------------------------------------------------------------------------
__global__ __launch_bounds__(256) void gemm_qkv(
    const unsigned short* __restrict__ X,
    const unsigned short* __restrict__ WT,
    const float* __restrict__ bias,
    unsigned short* __restrict__ Qb,
    unsigned short* __restrict__ Kb,
    unsigned short* __restrict__ VTb)
{
    __shared__ alignas(16) unsigned short As[128 * 32];
    __shared__ alignas(16) unsigned short Bs[128 * 32];
    const int K = 1024;
    int t = threadIdx.x;
    int wave = t >> 6, lane = t & 63, quad = lane >> 4, l = lane & 15;
    int bm = blockIdx.x * 128, bn = blockIdx.y * 128;
    int wm = (wave >> 1) * 64, wn = (wave & 1) * 64;

    float4_t z = {0.f, 0.f, 0.f, 0.f};
    float4_t acc[4][4];
#pragma unroll
    for (int i = 0; i < 4; ++i)
#pragma unroll
        for (int j = 0; j < 4; ++j) acc[i][j] = z;

    for (int kt = 0; kt < K / 32; ++kt) {
        int k0 = kt * 32;
        if (kt) __syncthreads();
#pragma unroll
        for (int it = 0; it < 2; ++it) {
            int c = t + 256 * it;
            int row = c >> 2, col = (c & 3) * 8;
            gld_lds16(&X [(size_t)(bm + row) * K + k0 + col], &As[c * 8]);
            gld_lds16(&WT[(size_t)(bn + row) * K + k0 + col], &Bs[c * 8]);
        }
        __syncthreads();
        short8 af[4], bfr[4];
#pragma unroll
        for (int i = 0; i < 4; ++i)
            af[i] = *(const short8*)&As[(wm + i * 16 + l) * 32 + quad * 8];
#pragma unroll
        for (int j = 0; j < 4; ++j)
            bfr[j] = *(const short8*)&Bs[(wn + j * 16 + l) * 32 + quad * 8];
#pragma unroll
        for (int i = 0; i < 4; ++i)
#pragma unroll
            for (int j = 0; j < 4; ++j)
                acc[i][j] = __builtin_amdgcn_mfma_f32_16x16x32_bf16(
                    af[i], bfr[j], acc[i][j], 0, 0, 0);
    }
#pragma unroll
    for (int j = 0; j < 4; ++j) {
        int gc = bn + wn + j * 16 + l;
        float bv = bias[gc];
        int which = gc >> 10, rem = gc & 1023;
        int h = rem >> 6, d = rem & 63;
        if (which == 2) {
            int bb = bm >> 11;
            size_t rowbase = ((size_t)(bb * NH + h) * HD + d) * S_LEN;
#pragma unroll
            for (int i = 0; i < 4; ++i) {
                unsigned int u0 = __float_as_uint(acc[i][j][0] + bv) + 0x8000u;
                unsigned int u1 = __float_as_uint(acc[i][j][1] + bv) + 0x8000u;
                unsigned int u2 = __float_as_uint(acc[i][j][2] + bv) + 0x8000u;
                unsigned int u3 = __float_as_uint(acc[i][j][3] + bv) + 0x8000u;
                uint2 vv;
                vv.x = __builtin_amdgcn_perm(u1, u0, 0x07060302u);
                vv.y = __builtin_amdgcn_perm(u3, u2, 0x07060302u);
                int s0 = (bm + wm + i * 16 + quad * 4) & 2047;
                // permute keys within 64-group: pi(k)= quad_k*16 + t4*4 + r
                int k6 = s0 & 63;
                int s0p = (s0 & ~63) | (((k6 >> 2) & 3) << 4) | (((k6 >> 4) & 3) << 2);
                *(uint2*)&VTb[rowbase + s0p] = vv;
            }
        } else {
#pragma unroll
            for (int i = 0; i < 4; ++i)
#pragma unroll
                for (int r = 0; r < 4; ++r) {
                    int gr = bm + wm + i * 16 + quad * 4 + r;
                    int b = gr >> 11, s = gr & 2047;
                    float ov = acc[i][j][r] + bv;
                    size_t bh2 = (size_t)(b * NH + h);
                    if (which == 0) Qb[(bh2 * S_LEN + s) * HD + d] = f2bf(ov * QSCALE);
                    else            Kb[(bh2 * S_LEN + s) * HD + d] = f2bf(ov);
                }
        }
    }
}

// ---------------------------------------------------------------------------
// Flash attention (causal), LDS-staged K/V shared across the block.
//
// ROUND 7: R6 worked (77us) but each tile iteration paid a FULL
// vmcnt(0)+lgkmcnt(0) drain (__syncthreads before every compute): 32
// iterations x ~5.8K cyc on the critical block, mostly waiting on loads
// issued only ~600cy earlier.  Apply the verified counted-vmcnt pattern
// (T3/T4, m218: counted-vs-drain0 +38-73%):
//  - THREE 16KB K/V buffers (48KB LDS).  Per iteration:
//      wait vmcnt(4)  [tile u's own 4 loads/thread done; tile u+1's 4
//                      remain IN FLIGHT across the barrier]
//      raw s_barrier  [all waves' tile-u writes now visible]
//      sched_barrier(0)
//      stage(u+2)     [issue into the slot compute(u-1) just vacated]
//      compute(u)
//    Last iteration waits vmcnt(0) (uniform branch).  No drain-to-0 in
//    the steady-state loop.
//  - 48KB -> 3 blocks/CU resident; grid 1024 leaves 1 block/CU queued ->
//    backfill smooths the 17..32-iteration block-duration spread.
//  - v_cvt_pk_bf16_f32 (inline asm, no builtin) packs P: 1 inst/2 elems
//    replaces add+add+perm (manual bit-round was blocking compiler cvt_pk).
//  - diag mask split to a compile-time template path: non-diag tiles
//    (the vast majority) carry zero masking VALU.
// Everything else identical to R6 (balanced chunk assignment, permuted-V
// single-b128 PV reads, MFMA row-sum denominator, (256,2) bounds).
// ---------------------------------------------------------------------------
__global__ __launch_bounds__(256, 2) void flash_attn(
    const unsigned short* __restrict__ Qb,
    const unsigned short* __restrict__ Kb,
    const unsigned short* __restrict__ VTb,
    unsigned short* __restrict__ AO)
{
    // 3 buffers x (K 8KB | V 8KB) = 48KB; epilogue reuses first 8704B as
    // per-wave O staging (after full __syncthreads).
    __shared__ alignas(16) unsigned short smem[24576];

    int t = threadIdx.x, wave = t >> 6, lane = t & 63, quad = lane >> 4, cl = lane & 15;
    int blk = blockIdx.x;                        // 0..1023
    int bh = (blk & 7) + 8 * ((blk >> 3) & 7);   // XCD-pinned heads
    int g = blk >> 6;                            // 0..15
    int b = bh >> 4, h = bh & 15;
    int ci = (wave & 2) ? (62 - 2 * g + (wave & 1)) : (2 * g + (wave & 1));
    int qb = 32 * ci;
    int nkt = (ci >> 1) + 1;                     // tiles this wave computes
    int nkt_max = 32 - g;                        // tiles the block stages (>=17)

    const unsigned short* Qbase = Qb  + (size_t)bh * S_LEN * HD;
    const unsigned short* Kbase = Kb  + (size_t)bh * S_LEN * HD;
    const unsigned short* Vbase = VTb + (size_t)bh * HD * S_LEN;

    float4_t z = {0.f, 0.f, 0.f, 0.f};
    short8 onesf;
#pragma unroll
    for (int i = 0; i < 8; ++i) onesf[i] = (short)0x3F80;   // bf16 1.0

    short8 bQ[2][2];
#pragma unroll
    for (int qt = 0; qt < 2; ++qt)
#pragma unroll
        for (int hh = 0; hh < 2; ++hh)
            bQ[qt][hh] = *(const short8*)&Qbase[(size_t)(qb + qt * 16 + cl) * HD + hh * 32 + quad * 8];

    float4_t acc[2][4], accs[2];
#pragma unroll
    for (int qt = 0; qt < 2; ++qt) {
        accs[qt] = z;
#pragma unroll
        for (int nb = 0; nb < 4; ++nb) acc[qt][nb] = z;
    }

    // kt-invariant swizzled LDS read offsets (bytes, relative to buffer base)
    int koff0[4], koff1[4];
#pragma unroll
    for (int t4 = 0; t4 < 4; ++t4) {
        int row = t4 * 16 + cl, sw = row & 7;
        koff0[t4] = (row << 7) | ((quad ^ sw) << 4);
        koff1[t4] = (row << 7) | (((quad + 4) ^ sw) << 4);
    }
    // V (permuted layout): B-frag for (p,quad) at 16B slot (quad*2+p)^(row&7)
    int voffB[2][4];
#pragma unroll
    for (int p = 0; p < 2; ++p)
#pragma unroll
        for (int nb = 0; nb < 4; ++nb) {
            int row = nb * 16 + cl;
            voffB[p][nb] = 8192 + ((row << 7) | (((quad * 2 + p) ^ (row & 7)) << 4));
        }

    auto stage = [&](int kt, int slot) {
        int key0 = kt << 6;
        unsigned short* Kd = smem + slot * 8192;   // 16KB per slot (in shorts)
        unsigned short* Vd = Kd + 4096;
#pragma unroll
        for (int i = 0; i < 2; ++i) {
            int s = t + 256 * i;
            int row = s >> 3, c16 = (s & 7) ^ (row & 7);
            gld_lds16(&Kbase[(size_t)(key0 + row) * HD + c16 * 8], &Kd[s * 8]);
            gld_lds16(&Vbase[(size_t)row * S_LEN + key0 + c16 * 8], &Vd[s * 8]);
        }
    };

    auto compute = [&](auto DIAGC, int slot, int key0) {
        constexpr bool DIAG = decltype(DIAGC)::v;
        const char* Kc = (const char*)(smem + slot * 8192);
        short8 aK0[4], aK1[4];
#pragma unroll
        for (int t4 = 0; t4 < 4; ++t4) {
            aK0[t4] = *(const short8*)(Kc + koff0[t4]);
            aK1[t4] = *(const short8*)(Kc + koff1[t4]);
        }
        U8 bv[2][4];
#pragma unroll
        for (int p = 0; p < 2; ++p)
#pragma unroll
            for (int nb = 0; nb < 4; ++nb)
                bv[p][nb].i = *(const int4_t*)(Kc + voffB[p][nb]);

#pragma unroll
        for (int qt = 0; qt < 2; ++qt) {
            unsigned int pk[4][2];
#pragma unroll
            for (int t4 = 0; t4 < 4; ++t4) {
                float4_t st = __builtin_amdgcn_mfma_f32_16x16x32_bf16(
                    aK1[t4], bQ[qt][1],
                    __builtin_amdgcn_mfma_f32_16x16x32_bf16(aK0[t4], bQ[qt][0], z, 0, 0, 0),
                    0, 0, 0);
                float e[4];
#pragma unroll
                for (int r = 0; r < 4; ++r) {
                    e[r] = __builtin_amdgcn_exp2f(st[r]);      // Q pre-scaled
                    if (DIAG) {
                        int key = key0 + t4 * 16 + quad * 4 + r;
                        e[r] = (key <= qb + qt * 16 + cl) ? e[r] : 0.f;
                    }
                }
                pk[t4][0] = cvtpk_bf16(e[0], e[1]);
                pk[t4][1] = cvtpk_bf16(e[2], e[3]);
            }
#pragma unroll
            for (int p = 0; p < 2; ++p) {
                U8 a; a.i = (int4_t){(int)pk[2 * p][0], (int)pk[2 * p][1],
                                     (int)pk[2 * p + 1][0], (int)pk[2 * p + 1][1]};
                accs[qt] = __builtin_amdgcn_mfma_f32_16x16x32_bf16(
                    a.s, onesf, accs[qt], 0, 0, 0);            // row-sum (denominator)
#pragma unroll
                for (int nb = 0; nb < 4; ++nb)
                    acc[qt][nb] = __builtin_amdgcn_mfma_f32_16x16x32_bf16(
                        a.s, bv[p][nb].s, acc[qt][nb], 0, 0, 0);
            }
        }
    };

    // --- counted-vmcnt 3-slot pipeline ---
    stage(0, 0);
    if (nkt_max > 1) stage(1, 1);          // nkt_max >= 17 always, but be safe
    int cb = 0, sb = 2;                    // compute slot, stage slot
    for (int u = 0; u < nkt_max; ++u) {
        if (u + 1 < nkt_max) {
            asm volatile("s_waitcnt vmcnt(4)" ::: "memory");  // own tile-u loads done
        } else {
            asm volatile("s_waitcnt vmcnt(0)" ::: "memory");  // final tile
        }
        __builtin_amdgcn_s_barrier();      // all waves' tile-u writes visible
        __builtin_amdgcn_sched_barrier(0);
        if (u + 2 < nkt_max) stage(u + 2, sb);   // slot vacated by compute(u-1)
        if (u < nkt) {
            if (u == nkt - 1) compute(BoolC<true>{},  cb, u << 6);
            else              compute(BoolC<false>{}, cb, u << 6);
        }
        cb = (cb == 2) ? 0 : cb + 1;
        sb = (sb == 2) ? 0 : sb + 1;
    }

    __syncthreads();   // full drain; all waves done with K/V LDS before stg aliasing
    unsigned short* stgw = smem + wave * 1088;   // 16 rows x 68 stride (2176B)

    // epilogue: normalize + coalesced store via per-wave LDS staging
#pragma unroll
    for (int qt = 0; qt < 2; ++qt) {
        float fr[4];
#pragma unroll
        for (int r = 0; r < 4; ++r) fr[r] = 1.f / accs[qt][r];
#pragma unroll
        for (int nb = 0; nb < 4; ++nb)
#pragma unroll
            for (int r = 0; r < 4; ++r) {
                unsigned int uu = __float_as_uint(acc[qt][nb][r] * fr[r]) + 0x8000u;
                stgw[(quad * 4 + r) * 68 + nb * 16 + cl] = (unsigned short)(uu >> 16);
            }
#pragma unroll
        for (int pass = 0; pass < 4; ++pass) {
            int idx = pass * 64 + lane;
            int row = idx >> 4, part = idx & 15;
            ushort4 v = *(const ushort4*)&stgw[row * 68 + part * 4];
            *(ushort4*)&AO[((size_t)b * S_LEN + qb + qt * 16 + row) * EMB + h * HD + part * 4] = v;
        }
    }
}

// ---------------------------------------------------------------------------
// GEMM2: out_f32 = AO[8192,1024]bf16 @ WoutT[1024,1024]^T + bout(f32)
// ---------------------------------------------------------------------------
__global__ __launch_bounds__(256) void gemm_out(
    const unsigned short* __restrict__ A,
    const unsigned short* __restrict__ WT,
    const float* __restrict__ bias,
    float* __restrict__ out)
{
    __shared__ alignas(16) unsigned short As[128 * 32];
    __shared__ alignas(16) unsigned short Bs[128 * 32];
    const int K = 1024;
    int t = threadIdx.x;
    int wave = t >> 6, lane = t & 63, quad = lane >> 4, l = lane & 15;
    int bm = blockIdx.x * 128, bn = blockIdx.y * 128;
    int wm = (wave >> 1) * 64, wn = (wave & 1) * 64;

    float4_t z = {0.f, 0.f, 0.f, 0.f};
    float4_t acc[4][4];
#pragma unroll
    for (int i = 0; i < 4; ++i)
#pragma unroll
        for (int j = 0; j < 4; ++j) acc[i][j] = z;

    for (int kt = 0; kt < K / 32; ++kt) {
        int k0 = kt * 32;
        if (kt) __syncthreads();
#pragma unroll
        for (int it = 0; it < 2; ++it) {
            int c = t + 256 * it;
            int row = c >> 2, col = (c & 3) * 8;
            gld_lds16(&A [(size_t)(bm + row) * K + k0 + col], &As[c * 8]);
            gld_lds16(&WT[(size_t)(bn + row) * K + k0 + col], &Bs[c * 8]);
        }
        __syncthreads();
        short8 af[4], bfr[4];
#pragma unroll
        for (int i = 0; i < 4; ++i)
            af[i] = *(const short8*)&As[(wm + i * 16 + l) * 32 + quad * 8];
#pragma unroll
        for (int j = 0; j < 4; ++j)
            bfr[j] = *(const short8*)&Bs[(wn + j * 16 + l) * 32 + quad * 8];
#pragma unroll
        for (int i = 0; i < 4; ++i)
#pragma unroll
            for (int j = 0; j < 4; ++j)
                acc[i][j] = __builtin_amdgcn_mfma_f32_16x16x32_bf16(
                    af[i], bfr[j], acc[i][j], 0, 0, 0);
    }
#pragma unroll
    for (int j = 0; j < 4; ++j) {
        int gc = bn + wn + j * 16 + l;
        float bv = bias[gc];
#pragma unroll
        for (int i = 0; i < 4; ++i) {
#pragma unroll
            for (int r = 0; r < 4; ++r) {
                int gr = bm + wm + i * 16 + quad * 4 + r;
                out[(size_t)gr * EMB + gc] = acc[i][j][r] + bv;
            }
        }
    }
}

// ---------------------------------------------------------------------------
extern "C" void kernel_launch(void* const* d_in, const int* in_sizes, int n_in,
                              void* d_out, int out_size, void* d_ws, size_t ws_size,
                              hipStream_t stream) {
    const float* x    = (const float*)d_in[0];
    // d_in[1] = causal mask (int32 tril) -- implemented analytically, not read
    const float* Wqkv = (const float*)d_in[2];
    const float* bqkv = (const float*)d_in[3];
    const float* Wout = (const float*)d_in[4];
    const float* bout = (const float*)d_in[5];
    float* out = (float*)d_out;

    // workspace (bf16): Q 16MB | K 16MB | VT 16MB | Xb/AO 16MB (aliased) |
    // WqkvT 6MB | WoutT 2MB = 72MB
    char* ws = (char*)d_ws;
    const size_t SZ = (size_t)NB * NH * S_LEN * HD * 2;  // 16 MiB
    unsigned short* Qb    = (unsigned short*)(ws);
    unsigned short* Kb    = (unsigned short*)(ws + SZ);
    unsigned short* VTb   = (unsigned short*)(ws + 2 * SZ);
    unsigned short* Xb    = (unsigned short*)(ws + 3 * SZ);
    unsigned short* AO    = (unsigned short*)(ws + 3 * SZ);  // alias with Xb
    unsigned short* WqkvT = (unsigned short*)(ws + 4 * SZ);
    unsigned short* WoutT = (unsigned short*)(ws + 4 * SZ + (size_t)3 * EMB * EMB * 2);

    int n2 = MROWS * EMB / 2;
    cvt_f32_bf16<<<dim3((n2 + 255) / 256), 256, 0, stream>>>(x, Xb, n2);
    dim3 tb(32, 8);
    transpose_f32_bf16<<<dim3(3 * EMB / 32, EMB / 32), tb, 0, stream>>>(Wqkv, WqkvT, EMB, 3 * EMB);
    transpose_f32_bf16<<<dim3(EMB / 32, EMB / 32), tb, 0, stream>>>(Wout, WoutT, EMB, EMB);
    gemm_qkv<<<dim3(MROWS / 128, 3 * EMB / 128), 256, 0, stream>>>(Xb, WqkvT, bqkv, Qb, Kb, VTb);
    flash_attn<<<dim3(1024), 256, 0, stream>>>(Qb, Kb, VTb, AO);
    gemm_out<<<dim3(MROWS / 128, EMB / 128), 256, 0, stream>>>(AO, WoutT, bout, out);
}